// Round 12
// baseline (77.606 us; speedup 1.0000x reference)
//
#include <hip/hip_runtime.h>

#define NN 32
#define CC 256
#define KK 8192
#define PARTS 16
#define TPB 256
#define PSTR 640            // perm entries per part; 40 per lane
#define CH 8                // rows per block -> grid 1024
#define NCH (CC / CH)       // 32
#define MAX_INIT (-100.0f)

typedef unsigned int uint32;
typedef unsigned short u16;

// ---------------------------------------------------------------------------
// ws: pcount int[16] @0; permbase u16[16*640] @64; bitmask u32[32*256] @24576.
// perm entry: k (13b) | pad-flag 0x4000; pads replicate bucket's first real k.
// permbase layout is TRANSPOSED: entry for sorted rank q = i*16+l of part p is
// stored at permbase[p*640 + l*40 + i] -> lane l's 40 entries are contiguous
// (one 80B load) while consecutive i (the gather loop) walk consecutive
// sorted ranks ACROSS the 16 lanes of a group -> a wave's 64 addresses at
// step i sit in a ~1-2 KB k-window -> global gather coalesces to ~8-16
// 128B-line transactions/instr and L1 (32 KB = one row) gives ~16x reuse.
// ---------------------------------------------------------------------------

// grid 48: blocks 0..15 = stable bucket-select for part p (one scan each);
//          blocks 16..47 = vm bitmask compaction for n = blk-16.
__global__ __launch_bounds__(TPB) void prep_kernel(const int* __restrict__ labels,
                                                   const int* __restrict__ vm,
                                                   int* __restrict__ pcount,
                                                   u16* __restrict__ permbase,
                                                   uint32* __restrict__ bmask) {
    const int t = threadIdx.x;
    const int blk = blockIdx.x;

    if (blk >= PARTS) {
        // ---- bitmask block: n = blk-16 ----
        const int n = blk - PARTS;
        const int4* v4 = (const int4*)(vm + (size_t)n * KK) + t * 8;
        uint32 bits = 0;
#pragma unroll
        for (int j = 0; j < 8; ++j) {
            int4 v = v4[j];
            bits |= (uint32)(v.x != 0) << (4 * j) | (uint32)(v.y != 0) << (4 * j + 1) |
                    (uint32)(v.z != 0) << (4 * j + 2) | (uint32)(v.w != 0) << (4 * j + 3);
        }
        bmask[n * 256 + t] = bits;
        return;
    }

    // ---- bucket-select block for part p = blk ----
    const int p = blk;
    __shared__ __align__(16) u16 sperm[PSTR];
    __shared__ u16 wtot[4];
    __shared__ uint32 stot;
    const int w = t >> 6;
    const int lane = t & 63;

    int4 lv[8];
    const int4* l4 = (const int4*)labels + t * 8;  // k = t*32 + j*4 + c
#pragma unroll
    for (int j = 0; j < 8; ++j) lv[j] = l4[j];

    uint32 c = 0;
#pragma unroll
    for (int j = 0; j < 8; ++j) {
        c += ((lv[j].x & 15) == p) + ((lv[j].y & 15) == p) +
             ((lv[j].z & 15) == p) + ((lv[j].w & 15) == p);
    }
    // exclusive scan over 256 threads
    uint32 inc = c;
#pragma unroll
    for (int s = 1; s < 64; s <<= 1) {
        uint32 o = __shfl_up(inc, s, 64);
        if (lane >= s) inc += o;
    }
    if (lane == 63) wtot[w] = (u16)inc;
    __syncthreads();
    uint32 base = inc - c;
    for (int ww = 0; ww < w; ++ww) base += wtot[ww];
    if (t == TPB - 1) stot = base + c;

    // stable scatter (ascending k within thread, scan across threads)
    uint32 pos = base;
#pragma unroll
    for (int j = 0; j < 8; ++j) {
        int la[4] = {lv[j].x, lv[j].y, lv[j].z, lv[j].w};
#pragma unroll
        for (int cc = 0; cc < 4; ++cc) {
            if ((la[cc] & 15) == p) {
                if (pos < PSTR) sperm[pos] = (u16)(t * 32 + j * 4 + cc);
                ++pos;
            }
        }
    }
    __syncthreads();

    const uint32 total = stot;
    const u16 fill = (u16)((total ? (sperm[0] & 0x1fffu) : 0u) | 0x4000u);
    for (uint32 q = total + t; q < PSTR; q += TPB) sperm[q] = fill;
    if (t == 0) pcount[p] = (int)total;
    __syncthreads();

    // transposed writeout: rank q = i*16+l  ->  permbase[p*640 + l*40 + i]
    for (uint32 q = t; q < PSTR; q += TPB) {
        u16 v = sperm[q];
        permbase[p * PSTR + (q & 15u) * 40u + (q >> 4)] = v;
    }
}

// Pool: grid 1024 (n x 8-row chunk), NO barriers, NO LDS data staging.
// Perm (transposed) + global byte-offsets + 40-bit validity pre-decoded to
// registers; each thread gathers 40 scattered dwords per row DIRECTLY from
// global (sorted-order interleave -> wave-coherent ~1-2KB windows -> L1/L2
// absorb the 16x line reuse). Waves run fully independent at high occupancy.
__global__ __launch_bounds__(TPB) void pool_kernel(const float* __restrict__ feats,
                                                   const u16* __restrict__ permbase,
                                                   const int* __restrict__ pcount,
                                                   const uint32* __restrict__ bmask,
                                                   float* __restrict__ out) {
    __shared__ uint32 smask[256];  // 1 KB vm bitmask for this n
    const int t = threadIdx.x;
    const int blk = blockIdx.x;
    const int n = blk / NCH;
    const int c0 = (blk % NCH) * CH;
    const int g = t >> 4;  // part owned by this 16-thread group
    const int l = t & 15;

    smask[t] = bmask[n * 256 + t];

    uint32 pk[20];
    {
        const uint4* pb4 = (const uint4*)(permbase + g * PSTR + l * 40);  // 80 B/lane
#pragma unroll
        for (int j = 0; j < 5; ++j) {
            uint4 q = pb4[j];
            pk[j * 4 + 0] = q.x;
            pk[j * 4 + 1] = q.y;
            pk[j * 4 + 2] = q.z;
            pk[j * 4 + 3] = q.w;
        }
    }
    __syncthreads();  // smask visible

    // pre-decode: packed global byte-offsets (2 u16 per reg) + 40-bit mask
    uint32 pa[20];
    uint32 vb0 = 0, vb1 = 0;
    int cnt = 0;
#pragma unroll
    for (int j = 0; j < 20; ++j) {
        uint32 two = pk[j];
        uint32 packed = 0;
#pragma unroll
        for (int h = 0; h < 2; ++h) {
            uint32 e = (two >> (16 * h)) & 0xffffu;
            uint32 k = e & 0x1fffu;
            uint32 valid = (e & 0x4000u) ? 0u : ((smask[k >> 5] >> (k & 31u)) & 1u);
            packed |= (k * 4u) << (16 * h);  // byte offset, fits u16
            int i = j * 2 + h;
            if (i < 32) vb0 |= valid << i;
            else        vb1 |= valid << (i - 32);
            cnt += (int)valid;
        }
        pa[j] = packed;
    }
#pragma unroll
    for (int m = 1; m < 16; m <<= 1) cnt += __shfl_xor(cnt, m, 16);
    const float cv = fmaxf((float)cnt, 1.0f);
    const int ph = pcount[g];

#define ACC(IDX, F, RS, RM)                                         \
    do {                                                            \
        RM = fmaxf(RM, (F));                                        \
        uint32 vb_ = ((IDX) < 32) ? vb0 : vb1;                      \
        RS += ((vb_ >> ((IDX) & 31)) & 1u) ? (F) : 0.0f;            \
    } while (0)

    for (int r = 0; r < CH; ++r) {
        const char* rowb = (const char*)(feats + (size_t)(n * CC + c0 + r) * KK);
        float rs0 = 0.0f, rs1 = 0.0f, rs2 = 0.0f, rs3 = 0.0f;
        float rm0 = MAX_INIT, rm1 = MAX_INIT, rm2 = MAX_INIT, rm3 = MAX_INIT;
#pragma unroll
        for (int j = 0; j < 20; j += 4) {  // 8 gathers per batch, 5 batches
            uint32 p0 = pa[j];
            uint32 p1 = pa[j + 1];
            uint32 p2 = pa[j + 2];
            uint32 p3 = pa[j + 3];
            float f0 = *(const float*)(rowb + (p0 & 0xffffu));
            float f1 = *(const float*)(rowb + (p0 >> 16));
            float f2 = *(const float*)(rowb + (p1 & 0xffffu));
            float f3 = *(const float*)(rowb + (p1 >> 16));
            float f4 = *(const float*)(rowb + (p2 & 0xffffu));
            float f5 = *(const float*)(rowb + (p2 >> 16));
            float f6 = *(const float*)(rowb + (p3 & 0xffffu));
            float f7 = *(const float*)(rowb + (p3 >> 16));
            ACC(j * 2 + 0, f0, rs0, rm0);
            ACC(j * 2 + 1, f1, rs1, rm1);
            ACC(j * 2 + 2, f2, rs2, rm2);
            ACC(j * 2 + 3, f3, rs3, rm3);
            ACC(j * 2 + 4, f4, rs0, rm0);
            ACC(j * 2 + 5, f5, rs1, rm1);
            ACC(j * 2 + 6, f6, rs2, rm2);
            ACC(j * 2 + 7, f7, rs3, rm3);
        }
        float rs = (rs0 + rs1) + (rs2 + rs3);
        float rm = fmaxf(fmaxf(rm0, rm1), fmaxf(rm2, rm3));
#pragma unroll
        for (int m = 1; m < 16; m <<= 1) {
            rs += __shfl_xor(rs, m, 16);
            rm = fmaxf(rm, __shfl_xor(rm, m, 16));
        }
        if (l == 0)
            out[(size_t)(n * CC + c0 + r) * PARTS + g] = rs / cv + (ph > 0 ? rm : 0.0f);
    }
#undef ACC
}

extern "C" void kernel_launch(void* const* d_in, const int* in_sizes, int n_in,
                              void* d_out, int out_size, void* d_ws, size_t ws_size,
                              hipStream_t stream) {
    const float* feats  = (const float*)d_in[0];
    const int*   labels = (const int*)d_in[1];
    const int*   vm     = (const int*)d_in[2];
    float* out = (float*)d_out;

    int*    pcount   = (int*)d_ws;
    u16*    permbase = (u16*)((char*)d_ws + 64);
    uint32* bmask    = (uint32*)((char*)d_ws + 24576);

    prep_kernel<<<PARTS + NN, TPB, 0, stream>>>(labels, vm, pcount, permbase, bmask);
    pool_kernel<<<NN * NCH, TPB, 0, stream>>>(feats, permbase, pcount, bmask, out);
}

// Round 13
// 54.265 us; speedup vs baseline: 1.4301x; 1.4301x over previous
//
#include <hip/hip_runtime.h>

#define NN 32
#define CC 256
#define KK 8192
#define PARTS 16
#define TPB 256
#define PSTR 640            // perm entries per part; 40 per lane (mean 512 + 5.8 sigma)
#define CH 16               // rows per block -> grid 512 = 2 blocks/CU
#define NCH (CC / CH)       // 16
#define MAX_INIT (-100.0f)

typedef unsigned int uint32;
typedef unsigned short u16;

// LDS row swizzle (16B granules), involution; applied on BOTH sides
// (pre-swizzled global source for global_load_lds + swizzled read addr).
__device__ __forceinline__ uint32 swz(uint32 g) {
    return g ^ (((g >> 3) ^ (g >> 6)) & 7u);
}

// ---------------------------------------------------------------------------
// ws: pcount int[16] @0; permbase u16[16*640] @64; bitmask u32[32*256] @24576.
// perm entry: k (13b) | pad-flag 0x4000; pads replicate bucket's first real k.
// ---------------------------------------------------------------------------

// grid 48: blocks 0..15 = stable bucket-select for part p (one scan each);
//          blocks 16..47 = vm bitmask compaction for n = blk-16.
__global__ __launch_bounds__(TPB) void prep_kernel(const int* __restrict__ labels,
                                                   const int* __restrict__ vm,
                                                   int* __restrict__ pcount,
                                                   u16* __restrict__ permbase,
                                                   uint32* __restrict__ bmask) {
    const int t = threadIdx.x;
    const int blk = blockIdx.x;

    if (blk >= PARTS) {
        // ---- bitmask block: n = blk-16 ----
        const int n = blk - PARTS;
        const int4* v4 = (const int4*)(vm + (size_t)n * KK) + t * 8;
        uint32 bits = 0;
#pragma unroll
        for (int j = 0; j < 8; ++j) {
            int4 v = v4[j];
            bits |= (uint32)(v.x != 0) << (4 * j) | (uint32)(v.y != 0) << (4 * j + 1) |
                    (uint32)(v.z != 0) << (4 * j + 2) | (uint32)(v.w != 0) << (4 * j + 3);
        }
        bmask[n * 256 + t] = bits;
        return;
    }

    // ---- bucket-select block for part p = blk ----
    const int p = blk;
    __shared__ __align__(16) u16 sperm[PSTR];
    __shared__ u16 wtot[4];
    __shared__ uint32 stot;
    const int w = t >> 6;
    const int lane = t & 63;

    int4 lv[8];
    const int4* l4 = (const int4*)labels + t * 8;  // k = t*32 + j*4 + c
#pragma unroll
    for (int j = 0; j < 8; ++j) lv[j] = l4[j];

    uint32 c = 0;
#pragma unroll
    for (int j = 0; j < 8; ++j) {
        c += ((lv[j].x & 15) == p) + ((lv[j].y & 15) == p) +
             ((lv[j].z & 15) == p) + ((lv[j].w & 15) == p);
    }
    // exclusive scan over 256 threads
    uint32 inc = c;
#pragma unroll
    for (int s = 1; s < 64; s <<= 1) {
        uint32 o = __shfl_up(inc, s, 64);
        if (lane >= s) inc += o;
    }
    if (lane == 63) wtot[w] = (u16)inc;
    __syncthreads();
    uint32 base = inc - c;
    for (int ww = 0; ww < w; ++ww) base += wtot[ww];
    if (t == TPB - 1) stot = base + c;

    // stable scatter (ascending k within thread, scan across threads)
    uint32 pos = base;
#pragma unroll
    for (int j = 0; j < 8; ++j) {
        int la[4] = {lv[j].x, lv[j].y, lv[j].z, lv[j].w};
#pragma unroll
        for (int cc = 0; cc < 4; ++cc) {
            if ((la[cc] & 15) == p) {
                if (pos < PSTR) sperm[pos] = (u16)(t * 32 + j * 4 + cc);
                ++pos;
            }
        }
    }
    __syncthreads();

    const uint32 total = stot;
    const u16 fill = (u16)((total ? (sperm[0] & 0x1fffu) : 0u) | 0x4000u);
    for (uint32 q = total + t; q < PSTR; q += TPB) sperm[q] = fill;
    if (t == 0) pcount[p] = (int)total;
    __syncthreads();

    const uint4* src = (const uint4*)sperm;
    uint4* dst = (uint4*)(permbase + p * PSTR);  // 80 uint4
    for (int i = t; i < PSTR * 2 / 16; i += TPB) dst[i] = src[i];
}

// Pool: grid 512, 2 blocks/CU. Perm + swizzled addrs + 0/1 masks pre-decoded
// to registers; bitmask from precomputed global (1 KB, own LDS array). Rows
// double-buffer through 64 KiB LDS via global_load_lds, counted vmcnt(8);
// rows 0+1 pre-staged so predecode hides under first-row HBM latency.
__global__ __launch_bounds__(TPB, 2) void pool_kernel(const float* __restrict__ feats,
                                                      const u16* __restrict__ permbase,
                                                      const int* __restrict__ pcount,
                                                      const uint32* __restrict__ bmask,
                                                      float* __restrict__ out) {
    __shared__ uint32 srow[2 * KK];   // 64 KiB row buffers
    __shared__ uint32 smask[256];     // 1 KB vm bitmask for this n
    const int t = threadIdx.x;
    const int blk = blockIdx.x;
    const int n = blk / NCH;
    const int c0 = (blk % NCH) * CH;
    const int w = t >> 6;
    const int lane = t & 63;
    const int g = t >> 4;  // part owned by this 16-thread group
    const int l = t & 15;

    // pre-swizzled global source offsets for staging (8 per wave)
    uint32 woff[8];
#pragma unroll
    for (int i = 0; i < 8; ++i) {
        uint32 r = (uint32)(w * 8 + i) * 64u + (uint32)lane;  // linear dest granule
        woff[i] = swz(r) * 4u;                                // global word offset
    }

    auto STAGE = [&](int buf, int r) {
        const uint32* frow = (const uint32*)(feats + (size_t)(n * CC + c0 + r) * KK);
#pragma unroll
        for (int i = 0; i < 8; ++i) {
            __builtin_amdgcn_global_load_lds(
                (const __attribute__((address_space(1))) unsigned int*)(frow + woff[i]),
                (__attribute__((address_space(3))) unsigned int*)&srow[buf * KK + (w * 8 + i) * 256],
                16, 0, 0);
        }
    };

    // stage rows 0 and 1 immediately; prologue VALU hides under their latency
    STAGE(0, 0);
    STAGE(1, 1);

    smask[t] = bmask[n * 256 + t];

    uint32 pk[20];
    {
        const uint4* pb4 = (const uint4*)(permbase + g * PSTR + l * 40);  // 80 B/lane
#pragma unroll
        for (int j = 0; j < 5; ++j) {
            uint4 q = pb4[j];
            pk[j * 4 + 0] = q.x;
            pk[j * 4 + 1] = q.y;
            pk[j * 4 + 2] = q.z;
            pk[j * 4 + 3] = q.w;
        }
    }
    __syncthreads();  // smask visible

    // pre-decode: 40 swizzled LDS byte-addrs + 0/1 masks + valid count
    uint32 ga[40];
    float gm[40];
    int cnt = 0;
#pragma unroll
    for (int i = 0; i < 40; ++i) {
        uint32 e = (pk[i >> 1] >> (16 * (i & 1))) & 0xffffu;
        uint32 k = e & 0x1fffu;
        uint32 valid = (e & 0x4000u) ? 0u : ((smask[k >> 5] >> (k & 31u)) & 1u);
        uint32 pos = swz(k >> 2);
        ga[i] = pos * 16u + (k & 3u) * 4u;
        gm[i] = valid ? 1.0f : 0.0f;
        cnt += (int)valid;
    }
#pragma unroll
    for (int m = 1; m < 16; m <<= 1) cnt += __shfl_xor(cnt, m, 16);
    const float cv = fmaxf((float)cnt, 1.0f);
    const int ph = pcount[g];

    for (int r = 0; r < CH; ++r) {
        if (r < CH - 1) {
            asm volatile("s_waitcnt vmcnt(8)" ::: "memory");  // row r landed
        } else {
            asm volatile("s_waitcnt vmcnt(0)" ::: "memory");
        }
        __builtin_amdgcn_s_barrier();

        const char* rowb = (const char*)&srow[(r & 1) * KK];
        float rs0 = 0.0f, rs1 = 0.0f, rs2 = 0.0f, rs3 = 0.0f;
        float rm0 = MAX_INIT, rm1 = MAX_INIT, rm2 = MAX_INIT, rm3 = MAX_INIT;
#pragma unroll
        for (int i = 0; i < 40; i += 4) {
            float f0 = *(const float*)(rowb + ga[i]);
            float f1 = *(const float*)(rowb + ga[i + 1]);
            float f2 = *(const float*)(rowb + ga[i + 2]);
            float f3 = *(const float*)(rowb + ga[i + 3]);
            rm0 = fmaxf(rm0, f0);
            rs0 = fmaf(f0, gm[i], rs0);
            rm1 = fmaxf(rm1, f1);
            rs1 = fmaf(f1, gm[i + 1], rs1);
            rm2 = fmaxf(rm2, f2);
            rs2 = fmaf(f2, gm[i + 2], rs2);
            rm3 = fmaxf(rm3, f3);
            rs3 = fmaf(f3, gm[i + 3], rs3);
        }
        float rs = (rs0 + rs1) + (rs2 + rs3);
        float rm = fmaxf(fmaxf(rm0, rm1), fmaxf(rm2, rm3));
#pragma unroll
        for (int m = 1; m < 16; m <<= 1) {
            rs += __shfl_xor(rs, m, 16);
            rm = fmaxf(rm, __shfl_xor(rm, m, 16));
        }
        if (l == 0)
            out[(size_t)(n * CC + c0 + r) * PARTS + g] = rs / cv + (ph > 0 ? rm : 0.0f);

        __builtin_amdgcn_s_barrier();          // all reads of buf[r&1] done
        if (r + 2 < CH) STAGE(r & 1, r + 2);   // refill freed buffer
    }
}

extern "C" void kernel_launch(void* const* d_in, const int* in_sizes, int n_in,
                              void* d_out, int out_size, void* d_ws, size_t ws_size,
                              hipStream_t stream) {
    const float* feats  = (const float*)d_in[0];
    const int*   labels = (const int*)d_in[1];
    const int*   vm     = (const int*)d_in[2];
    float* out = (float*)d_out;

    int*    pcount   = (int*)d_ws;
    u16*    permbase = (u16*)((char*)d_ws + 64);
    uint32* bmask    = (uint32*)((char*)d_ws + 24576);

    prep_kernel<<<PARTS + NN, TPB, 0, stream>>>(labels, vm, pcount, permbase, bmask);
    pool_kernel<<<NN * NCH, TPB, 0, stream>>>(feats, permbase, pcount, bmask, out);
}